// Round 1
// 26262.140 us; speedup vs baseline: 2.7281x; 2.7281x over previous
//
#include <hip/hip_runtime.h>

typedef unsigned short u16;
typedef unsigned int u32;
typedef unsigned long long u64;
typedef short short8 __attribute__((ext_vector_type(8)));
typedef float floatx4 __attribute__((ext_vector_type(4)));

#define SLEN 2048
#define BATCH 64
#define FDIM 512
#define HDIM 512
#define NWG 128
#define NTH 512
#define GROUPS 4
#define ROWS 16                        // batch rows per group
#define CPG 32                         // col-WGs per group
#define HROW_U32 (HDIM/2)              // 256 u32 per h row
#define HGRP_U32 (ROWS*HROW_U32)       // 4096 u32 per group buffer
#define HB_U32 (GROUPS*HGRP_U32)       // 16384 u32 per parity buffer
#define WS_BYTES (4096 + 2*HB_U32*4)   // flags pad + h double buffer

#define LDS_W_U16 (4*16*64*8)          // 32768 u16 per weight array
#define SCR_STRIDE (16*17)             // padded 16x16 f32 tile

// fp32 -> bf16 round-to-nearest-even
__device__ __forceinline__ u16 f2bf_rne(float f) {
  union { float f; u32 u; } v; v.f = f;
  u32 u = v.u + 0x7FFFu + ((v.u >> 16) & 1u);
  return (u16)(u >> 16);
}
__device__ __forceinline__ float sigmoidf_fast(float x) {
  return 1.0f / (1.0f + __expf(-x));
}
__device__ __forceinline__ float tanhf_fast(float x) {
  return 1.0f - 2.0f / (__expf(2.0f * x) + 1.0f);
}

// x-projection for one gate: A = x[16 batch rows][512] (per-lane row), B from LDS
// frag order. Writes 16x16 preact tile into padded scratch.
__device__ __forceinline__ void xpart_compute(
    const float* __restrict__ xrow, const u16* __restrict__ lds_wx,
    int gt, int lane, float* __restrict__ sx)
{
  const int kq = lane >> 4;
  const int m  = lane & 15;
  floatx4 accx = {0.f, 0.f, 0.f, 0.f};
#pragma unroll
  for (int kk = 0; kk < 16; ++kk) {
    floatx4 xa = *(const floatx4*)(xrow + kk*32 + (kq<<3));
    floatx4 xb = *(const floatx4*)(xrow + kk*32 + (kq<<3) + 4);
    short8 ax;
#pragma unroll
    for (int j = 0; j < 4; ++j) {
      ax[j]     = (short)f2bf_rne(xa[j]);
      ax[4 + j] = (short)f2bf_rne(xb[j]);
    }
    short8 bx = *(const short8*)(&lds_wx[((gt*16 + kk)*64 + lane)*8]);
    accx = __builtin_amdgcn_mfma_f32_16x16x32_bf16(ax, bx, accx, 0, 0, 0);
  }
  // C/D: col = lane&15 (=hcl), row = (lane>>4)*4 + r (=bl)
#pragma unroll
  for (int r = 0; r < 4; ++r)
    sx[((kq<<2) + r)*17 + m] = accx[r];
}

// Persistent grouped LSTM.
// WG (g = bid&3, c = bid>>2): batches [g*16, g*16+16), h-cols [c*16, c*16+16).
// Waves 0-3: recurrent (h) MFMA, gate=wave. Waves 4-7: x MFMA for step t+1, gate=wave-4.
// Sync: per-producer flag words flags[g*32 + c] = steps completed (monotonic).
__global__ __launch_bounds__(NTH, 1)
void lstm_persistent(
    const float* __restrict__ x,
    const float* __restrict__ w_ii, const float* __restrict__ b_ii,
    const float* __restrict__ w_hi, const float* __restrict__ b_hi,
    const float* __restrict__ w_if, const float* __restrict__ b_if,
    const float* __restrict__ w_hf, const float* __restrict__ b_hf,
    const float* __restrict__ w_ig, const float* __restrict__ b_ig,
    const float* __restrict__ w_hg, const float* __restrict__ b_hg,
    const float* __restrict__ w_io, const float* __restrict__ b_io,
    const float* __restrict__ w_ho, const float* __restrict__ b_ho,
    float* __restrict__ out, u32* __restrict__ flags, u32* __restrict__ hbuf)
{
  // B-frag order: lds[((gt*16+kk)*64 + lane)*8 + j] = W_gt[kk*32+(lane>>4)*8+j][c*16+(lane&15)]
  __shared__ u16 lds_wh[LDS_W_U16];          // 64 KiB
  __shared__ u16 lds_wx[LDS_W_U16];          // 64 KiB
  __shared__ float scr_h[4*SCR_STRIDE];      // h preacts, per gate, padded
  __shared__ float scr_x[2][4*SCR_STRIDE];   // x preacts, double-buffered by t parity

  const int tid  = threadIdx.x;
  const int g    = blockIdx.x & 3;
  const int c    = blockIdx.x >> 2;
  const int wv   = tid >> 6;
  const int lane = tid & 63;
  const int m    = lane & 15;
  const int kq   = lane >> 4;

  // one-time weight pack fp32 -> bf16 frag order
  {
    const float* WH[4] = {w_hi, w_hf, w_hg, w_ho};
    const float* WX[4] = {w_ii, w_if, w_ig, w_io};
    for (int idx = tid; idx < LDS_W_U16; idx += NTH) {
      int j  = idx & 7;
      int L  = (idx >> 3) & 63;
      int kk = (idx >> 9) & 15;
      int gt = idx >> 13;
      int k  = kk*32 + ((L >> 4) << 3) + j;
      int col = c*16 + (L & 15);
      lds_wh[idx] = f2bf_rne(WH[gt][k*HDIM + col]);
      lds_wx[idx] = f2bf_rne(WX[gt][k*HDIM + col]);
    }
  }

  // elementwise-state thread mapping (valid for tid < 256)
  const int bl  = (tid >> 4) & 15;
  const int hcl = tid & 15;
  const int col = c*16 + hcl;
  const float bias0 = b_ii[col] + b_hi[col];
  const float bias1 = b_if[col] + b_hf[col];
  const float bias2 = b_ig[col] + b_hg[col];
  const float bias3 = b_io[col] + b_ho[col];
  float c_reg = 0.f;

  const float* xbase = x + (size_t)(g*ROWS + m) * (SLEN * FDIM);
  u32* flg = flags + (g << 5);

  __syncthreads();   // weights ready

  // prologue: x preacts for t=0 into scr_x[0]
  if (wv >= 4)
    xpart_compute(xbase, lds_wx, wv - 4, lane, &scr_x[0][(wv - 4)*SCR_STRIDE]);

  for (int t = 0; t < SLEN; ++t) {
    // --- phase A: x-waves compute step t+1; wave 0 polls group flags ---
    if (wv >= 4) {
      if (t + 1 < SLEN)
        xpart_compute(xbase + (size_t)(t + 1)*FDIM, lds_wx, wv - 4, lane,
                      &scr_x[(t + 1) & 1][(wv - 4)*SCR_STRIDE]);
    } else if (tid < 64 && t > 0) {
      const u32* fp = flg + (lane & 31);   // 32 producers, monotonic flags
      while (__hip_atomic_load(fp, __ATOMIC_RELAXED, __HIP_MEMORY_SCOPE_AGENT) < (u32)t)
        __builtin_amdgcn_s_sleep(2);
    }
    __syncthreads();

    // --- phase B: h-waves load h_{t-1} and run recurrent MFMA ---
    if (wv < 4) {
      __builtin_amdgcn_fence(__ATOMIC_ACQUIRE, "agent");
      if (t > 0) {
        const u64* hrow = (const u64*)(hbuf + (t & 1)*HB_U32 + g*HGRP_U32 + m*HROW_U32);
        u64 hv0[16], hv1[16];
#pragma unroll
        for (int kk = 0; kk < 16; ++kk) {
          const int jd = kk*8 + (kq << 1);
          hv0[kk] = __hip_atomic_load(&hrow[jd],     __ATOMIC_RELAXED, __HIP_MEMORY_SCOPE_AGENT);
          hv1[kk] = __hip_atomic_load(&hrow[jd + 1], __ATOMIC_RELAXED, __HIP_MEMORY_SCOPE_AGENT);
        }
        floatx4 acc = {0.f, 0.f, 0.f, 0.f};
#pragma unroll
        for (int kk = 0; kk < 16; ++kk) {
          union { u64 q[2]; short8 s; } ha;
          ha.q[0] = hv0[kk]; ha.q[1] = hv1[kk];
          short8 bh = *(const short8*)(&lds_wh[((wv*16 + kk)*64 + lane)*8]);
          acc = __builtin_amdgcn_mfma_f32_16x16x32_bf16(ha.s, bh, acc, 0, 0, 0);
        }
#pragma unroll
        for (int r = 0; r < 4; ++r)
          scr_h[wv*SCR_STRIDE + ((kq << 2) + r)*17 + m] = acc[r];
      }
    }
    __syncthreads();

    // --- phase C: elementwise gates + state update (tid < 256) ---
    if (tid < 256) {
      const float* sx = scr_x[t & 1];
      const int off = bl*17 + hcl;
      float hi_ = 0.f, hf_ = 0.f, hg_ = 0.f, ho_ = 0.f;
      if (t > 0) {
        hi_ = scr_h[0*SCR_STRIDE + off];
        hf_ = scr_h[1*SCR_STRIDE + off];
        hg_ = scr_h[2*SCR_STRIDE + off];
        ho_ = scr_h[3*SCR_STRIDE + off];
      }
      float gi = sigmoidf_fast(sx[0*SCR_STRIDE + off] + hi_ + bias0);
      float gf = sigmoidf_fast(sx[1*SCR_STRIDE + off] + hf_ + bias1);
      float gg = tanhf_fast  (sx[2*SCR_STRIDE + off] + hg_ + bias2);
      float go = sigmoidf_fast(sx[3*SCR_STRIDE + off] + ho_ + bias3);
      c_reg = gf * c_reg + gi * gg;
      float h_new = go * tanhf_fast(c_reg);

      if (t == SLEN - 1) {
        out[(g*ROWS + bl)*HDIM + col]              = h_new;   // h
        out[BATCH*HDIM + (g*ROWS + bl)*HDIM + col] = c_reg;   // c
      } else {
        u32 hb = (u32)f2bf_rne(h_new);
        u32 other = (u32)__shfl_xor((int)hb, 1);   // partner hcl^1 (same wave)
        if ((hcl & 1) == 0) {
          u32 val = (other << 16) | hb;            // low u16 = even col
          __hip_atomic_store(
              &hbuf[((t + 1) & 1)*HB_U32 + g*HGRP_U32 + bl*HROW_U32 + (col >> 1)],
              val, __ATOMIC_RELAXED, __HIP_MEMORY_SCOPE_AGENT);
        }
      }
    }

    // --- phase D: publish flag (stores drained by barrier's vmcnt(0)) ---
    if (t < SLEN - 1) {
      __syncthreads();
      if (tid == 0) {
        __builtin_amdgcn_fence(__ATOMIC_RELEASE, "agent");
        __hip_atomic_store(&flg[c], (u32)(t + 1), __ATOMIC_RELEASE,
                           __HIP_MEMORY_SCOPE_AGENT);
      }
    }
  }
}

extern "C" void kernel_launch(void* const* d_in, const int* in_sizes, int n_in,
                              void* d_out, int out_size, void* d_ws, size_t ws_size,
                              hipStream_t stream) {
  // ws: [0,4096) per-producer flags (4 groups x 32 u32, padded);
  //     [4096, +128KiB) h double buffer (u32-packed bf16, [parity][group][row][256])
  u32* flags = (u32*)d_ws;
  u32* hbuf  = (u32*)((char*)d_ws + 4096);
  (void)hipMemsetAsync(d_ws, 0, WS_BYTES, stream);

  lstm_persistent<<<dim3(NWG), dim3(NTH), 0, stream>>>(
      (const float*)d_in[0],
      (const float*)d_in[1],  (const float*)d_in[2],   // w_ii, b_ii
      (const float*)d_in[3],  (const float*)d_in[4],   // w_hi, b_hi
      (const float*)d_in[5],  (const float*)d_in[6],   // w_if_, b_if_
      (const float*)d_in[7],  (const float*)d_in[8],   // w_hf, b_hf
      (const float*)d_in[9],  (const float*)d_in[10],  // w_ig, b_ig
      (const float*)d_in[11], (const float*)d_in[12],  // w_hg, b_hg
      (const float*)d_in[13], (const float*)d_in[14],  // w_io, b_io
      (const float*)d_in[15], (const float*)d_in[16],  // w_ho, b_ho
      (float*)d_out, flags, hbuf);
}

// Round 2
// 9168.178 us; speedup vs baseline: 7.8146x; 2.8645x over previous
//
#include <hip/hip_runtime.h>

typedef unsigned short u16;
typedef unsigned int u32;
typedef unsigned long long u64;
typedef short short8 __attribute__((ext_vector_type(8)));
typedef float floatx4 __attribute__((ext_vector_type(4)));

#define SLEN 2048
#define BATCH 64
#define FDIM 512
#define HDIM 512
#define NWG 128
#define NTH 192                        // 3 waves: wave0 = recurrent, waves 1-2 = x-proj
#define GROUPS 4
#define ROWS 16                        // batch rows per group
#define HROW_U32 (HDIM/2)              // 256 u32 per h row
#define HGRP_U32 (ROWS*HROW_U32)       // 4096 u32 per group
#define HB_U32 (GROUPS*HGRP_U32)       // 16384 u32 per parity buffer
#define WS_BYTES (4096 + 2*HB_U32*4)

#define LDS_W_U16 (4*16*64*8)          // 32768 u16 = 64 KiB per weight array
#define XR 20                          // padded row dim of scr_x (16B-aligned, bank-friendly)

// fp32 -> bf16 round-to-nearest-even
__device__ __forceinline__ u16 f2bf_rne(float f) {
  union { float f; u32 u; } v; v.f = f;
  u32 u = v.u + 0x7FFFu + ((v.u >> 16) & 1u);
  return (u16)(u >> 16);
}
__device__ __forceinline__ float sigmoidf_fast(float x) {
  return 1.0f / (1.0f + __expf(-x));
}
__device__ __forceinline__ float tanhf_fast(float x) {
  return 1.0f - 2.0f / (__expf(2.0f * x) + 1.0f);
}

// x-projection for two gates (g0, g0+1): A = x[16 rows][512], B from LDS frag order.
// Output tiles written col-major [col][row] into scr_x (one ds_write_b128 per gate).
__device__ __forceinline__ void x_gemm2(
    const float* __restrict__ xrow, const u16* __restrict__ lds_wx,
    int g0, int lane, int n, int kq, float* __restrict__ sd)
{
  floatx4 a0 = {0.f, 0.f, 0.f, 0.f};
  floatx4 a1 = {0.f, 0.f, 0.f, 0.f};
#pragma unroll
  for (int kk = 0; kk < 16; ++kk) {
    floatx4 xa = *(const floatx4*)(xrow + kk*32 + kq*8);
    floatx4 xb = *(const floatx4*)(xrow + kk*32 + kq*8 + 4);
    short8 ax;
#pragma unroll
    for (int j = 0; j < 4; ++j) {
      ax[j]     = (short)f2bf_rne(xa[j]);
      ax[4 + j] = (short)f2bf_rne(xb[j]);
    }
    short8 b0 = *(const short8*)&lds_wx[(((g0    )*16 + kk)*64 + lane)*8];
    short8 b1 = *(const short8*)&lds_wx[(((g0 + 1)*16 + kk)*64 + lane)*8];
    a0 = __builtin_amdgcn_mfma_f32_16x16x32_bf16(ax, b0, a0, 0, 0, 0);
    a1 = __builtin_amdgcn_mfma_f32_16x16x32_bf16(ax, b1, a1, 0, 0, 0);
  }
  // D layout: col = lane&15 (=n), row = kq*4 + r  ->  sd[gt][n][kq*4 + r]
  *(floatx4*)(sd + ((size_t)(g0    )*16 + n)*XR + kq*4) = a0;
  *(floatx4*)(sd + ((size_t)(g0 + 1)*16 + n)*XR + kq*4) = a1;
}

// Persistent grouped LSTM. WG (g = bid&3, c = bid>>2): batches [g*16,+16), h-cols [c*16,+16).
// wave0: poll flags -> load h (LLC atomics) -> 64 MFMA (all 4 gates) -> gates/state in-register
//        -> pack+store h -> vmcnt drain -> relaxed flag publish. No fences, no cache maintenance.
// waves 1-2: x preacts for step t+1 (2 gates each) into double-buffered LDS.
__global__ __launch_bounds__(NTH, 1)
void lstm_persistent(
    const float* __restrict__ x,
    const float* __restrict__ w_ii, const float* __restrict__ b_ii,
    const float* __restrict__ w_hi, const float* __restrict__ b_hi,
    const float* __restrict__ w_if, const float* __restrict__ b_if,
    const float* __restrict__ w_hf, const float* __restrict__ b_hf,
    const float* __restrict__ w_ig, const float* __restrict__ b_ig,
    const float* __restrict__ w_hg, const float* __restrict__ b_hg,
    const float* __restrict__ w_io, const float* __restrict__ b_io,
    const float* __restrict__ w_ho, const float* __restrict__ b_ho,
    float* __restrict__ out, u32* __restrict__ flags, u32* __restrict__ hbuf)
{
  // B-frag order: lds[((gt*16+kk)*64 + L)*8 + j] = W_gt[kk*32+(L>>4)*8+j][c*16+(L&15)]
  __shared__ __align__(16) u16 lds_wh[LDS_W_U16];        // 64 KiB
  __shared__ __align__(16) u16 lds_wx[LDS_W_U16];        // 64 KiB
  __shared__ __align__(16) float scr_x[2][4][16][XR];    // 10 KiB, col-major tiles

  const int tid  = threadIdx.x;
  const int g    = blockIdx.x & 3;
  const int c    = blockIdx.x >> 2;
  const int wv   = tid >> 6;
  const int lane = tid & 63;
  const int n    = lane & 15;     // A-frag row (batch) AND D col (h-col)
  const int kq   = lane >> 4;

  // one-time weight pack fp32 -> bf16 frag order (coalesced: 16 consecutive cols per row)
  {
    const float* WH[4] = {w_hi, w_hf, w_hg, w_ho};
    const float* WX[4] = {w_ii, w_if, w_ig, w_io};
    for (int idx = tid; idx < 4*512*16; idx += NTH) {
      int col  = idx & 15;
      int k    = (idx >> 4) & 511;
      int gt   = idx >> 13;
      int kk   = k >> 5, rem = k & 31, quad = rem >> 3, j = rem & 7;
      int di   = ((gt*16 + kk)*64 + quad*16 + col)*8 + j;
      int src  = k*HDIM + c*16 + col;
      lds_wh[di] = f2bf_rne(WH[gt][src]);
      lds_wx[di] = f2bf_rne(WX[gt][src]);
    }
  }

  const int col = c*16 + n;
  const float bias0 = b_ii[col] + b_hi[col];
  const float bias1 = b_if[col] + b_hf[col];
  const float bias2 = b_ig[col] + b_hg[col];
  const float bias3 = b_io[col] + b_ho[col];
  floatx4 c_st = {0.f, 0.f, 0.f, 0.f};

  const float* xbase = x + (size_t)(g*ROWS + n) * (SLEN * FDIM);
  u32* flg = flags + (g << 5);

  __syncthreads();   // weights ready

  // prologue: x preacts for t=0 into parity 0
  if (wv >= 1)
    x_gemm2(xbase, lds_wx, (wv - 1)*2, lane, n, kq, &scr_x[0][0][0][0]);

  for (int t = 0; t < SLEN; ++t) {
    __syncthreads();   // scr_x handoff (one barrier per step)

    if (wv >= 1) {
      if (t + 1 < SLEN)
        x_gemm2(xbase + (size_t)(t + 1)*FDIM, lds_wx, (wv - 1)*2, lane, n, kq,
                &scr_x[(t + 1) & 1][0][0][0]);
    } else {
      // x preacts for this step (written last iteration, safe after barrier)
      const float* sx = &scr_x[t & 1][0][0][0];
      floatx4 sxv0 = *(const floatx4*)(sx + (0*16 + n)*XR + kq*4);
      floatx4 sxv1 = *(const floatx4*)(sx + (1*16 + n)*XR + kq*4);
      floatx4 sxv2 = *(const floatx4*)(sx + (2*16 + n)*XR + kq*4);
      floatx4 sxv3 = *(const floatx4*)(sx + (3*16 + n)*XR + kq*4);

      floatx4 acc0 = {0.f,0.f,0.f,0.f}, acc1 = {0.f,0.f,0.f,0.f};
      floatx4 acc2 = {0.f,0.f,0.f,0.f}, acc3 = {0.f,0.f,0.f,0.f};

      if (t > 0) {
        // wait for all 32 producers of this group (per-lane spin, divergent exit = max)
        const u32* fp = flg + (lane & 31);
        while (__hip_atomic_load(fp, __ATOMIC_RELAXED, __HIP_MEMORY_SCOPE_AGENT) < (u32)t)
          __builtin_amdgcn_s_sleep(1);
        asm volatile("" ::: "memory");   // no hoisting of h loads above the poll

        const u64* hrow = (const u64*)(hbuf + (t & 1)*HB_U32 + g*HGRP_U32 + n*HROW_U32);
        u64 hv[32];
#pragma unroll
        for (int kk = 0; kk < 16; ++kk) {
          hv[2*kk]   = __hip_atomic_load(&hrow[kk*8 + kq*2],     __ATOMIC_RELAXED, __HIP_MEMORY_SCOPE_AGENT);
          hv[2*kk+1] = __hip_atomic_load(&hrow[kk*8 + kq*2 + 1], __ATOMIC_RELAXED, __HIP_MEMORY_SCOPE_AGENT);
        }
#pragma unroll
        for (int kk = 0; kk < 16; ++kk) {
          union { u64 q[2]; short8 s; } ha;
          ha.q[0] = hv[2*kk]; ha.q[1] = hv[2*kk+1];
          acc0 = __builtin_amdgcn_mfma_f32_16x16x32_bf16(ha.s, *(const short8*)&lds_wh[((0*16+kk)*64+lane)*8], acc0, 0,0,0);
          acc1 = __builtin_amdgcn_mfma_f32_16x16x32_bf16(ha.s, *(const short8*)&lds_wh[((1*16+kk)*64+lane)*8], acc1, 0,0,0);
          acc2 = __builtin_amdgcn_mfma_f32_16x16x32_bf16(ha.s, *(const short8*)&lds_wh[((2*16+kk)*64+lane)*8], acc2, 0,0,0);
          acc3 = __builtin_amdgcn_mfma_f32_16x16x32_bf16(ha.s, *(const short8*)&lds_wh[((3*16+kk)*64+lane)*8], acc3, 0,0,0);
        }
      }

      // gates + state, fully in-register (lane: batch rows kq*4+r, h-col n)
      float hnew[4];
#pragma unroll
      for (int r = 0; r < 4; ++r) {
        float gi = sigmoidf_fast(acc0[r] + sxv0[r] + bias0);
        float gf = sigmoidf_fast(acc1[r] + sxv1[r] + bias1);
        float gg = tanhf_fast  (acc2[r] + sxv2[r] + bias2);
        float go = sigmoidf_fast(acc3[r] + sxv3[r] + bias3);
        c_st[r] = gf * c_st[r] + gi * gg;
        hnew[r] = go * tanhf_fast(c_st[r]);
      }

      if (t == SLEN - 1) {
#pragma unroll
        for (int r = 0; r < 4; ++r) {
          int row = g*ROWS + kq*4 + r;
          out[row*HDIM + col]              = hnew[r];   // h
          out[BATCH*HDIM + row*HDIM + col] = c_st[r];   // c
        }
      } else {
        u32 hb[4];
#pragma unroll
        for (int r = 0; r < 4; ++r) hb[r] = (u32)f2bf_rne(hnew[r]);
        u32* hdst = hbuf + ((t + 1) & 1)*HB_U32 + g*HGRP_U32;
#pragma unroll
        for (int r = 0; r < 4; ++r) {
          u32 o = (u32)__shfl_xor((int)hb[r], 1);   // partner col n^1
          if ((n & 1) == 0) {
            u32 val = (o << 16) | hb[r];            // low u16 = even col
            __hip_atomic_store(&hdst[(kq*4 + r)*HROW_U32 + c*8 + (n >> 1)],
                               val, __ATOMIC_RELAXED, __HIP_MEMORY_SCOPE_AGENT);
          }
        }
        // h stores are sc-flagged write-through to LLC: drained == agent-visible.
        asm volatile("s_waitcnt vmcnt(0)" ::: "memory");
        if (tid == 0)
          __hip_atomic_store(&flg[c], (u32)(t + 1), __ATOMIC_RELAXED,
                             __HIP_MEMORY_SCOPE_AGENT);
      }
    }
  }
}

extern "C" void kernel_launch(void* const* d_in, const int* in_sizes, int n_in,
                              void* d_out, int out_size, void* d_ws, size_t ws_size,
                              hipStream_t stream) {
  // ws: [0,4096) per-producer flags (4 groups x 32 u32); [4096,+128KiB) h double buffer
  u32* flags = (u32*)d_ws;
  u32* hbuf  = (u32*)((char*)d_ws + 4096);
  (void)hipMemsetAsync(d_ws, 0, 4096, stream);   // flags must restart at 0 each replay

  lstm_persistent<<<dim3(NWG), dim3(NTH), 0, stream>>>(
      (const float*)d_in[0],
      (const float*)d_in[1],  (const float*)d_in[2],   // w_ii, b_ii
      (const float*)d_in[3],  (const float*)d_in[4],   // w_hi, b_hi
      (const float*)d_in[5],  (const float*)d_in[6],   // w_if_, b_if_
      (const float*)d_in[7],  (const float*)d_in[8],   // w_hf, b_hf
      (const float*)d_in[9],  (const float*)d_in[10],  // w_ig, b_ig
      (const float*)d_in[11], (const float*)d_in[12],  // w_hg, b_hg
      (const float*)d_in[13], (const float*)d_in[14],  // w_io, b_io
      (const float*)d_in[15], (const float*)d_in[16],  // w_ho, b_ho
      (float*)d_out, flags, hbuf);
}